// Round 4
// baseline (657.758 us; speedup 1.0000x reference)
//
#include <hip/hip_runtime.h>
#include <hip/hip_bf16.h>
#include <stdint.h>

// Castle attention, bf16 MFMA pipeline, split-flash version.
// convert -> qkv GEMM (LDS-staged slab epilogue) -> vcT transpose
//   -> tl (packed swizzled triangular tiles, coalesced writes)
//   -> castle (Su -> -silu -> +Sc -> mask -> local softmax -> PV partials)
//   -> combine (flash-merge) -> out GEMM.

typedef unsigned short u16;
typedef __attribute__((ext_vector_type(8))) short s8v;   // 8 x bf16
typedef __attribute__((ext_vector_type(4))) float f4v;   // MFMA accumulator

#define LDS_STRIDE 40

__device__ __forceinline__ u16 f2bf(float f) {
  union { float f; unsigned u; } v; v.f = f;
  unsigned r = v.u + 0x7FFFu + ((v.u >> 16) & 1u);
  return (u16)(r >> 16);
}
__device__ __forceinline__ float bf2f(u16 u) {
  union { unsigned u; float f; } v; v.u = ((unsigned)u) << 16; return v.f;
}

// swizzled element index within a 128-col (or 64-col) bf16 tile:
// byte ^= ((row&7)<<4)  ->  elem ^= ((row&7)<<3)
__device__ __forceinline__ int swz128(int r, int c) { return r * 128 + (c ^ ((r & 7) << 3)); }
__device__ __forceinline__ int swz64v(int r, int c) { return r * 64 + (c ^ ((r & 7) << 3)); }

typedef __attribute__((address_space(1))) const void* gas_t;
typedef __attribute__((address_space(3))) void* las_t;
__device__ __forceinline__ void gld16(const void* g, void* l) {
  __builtin_amdgcn_global_load_lds((gas_t)g, (las_t)l, 16, 0, 0);
}

__device__ __forceinline__ void stage_tile(u16* __restrict__ dst, const u16* __restrict__ src,
                                           int rows, long srcStride, int tid, int nthreads) {
  for (int i = tid; i < rows * 4; i += nthreads) {
    int r = i >> 2, seg = i & 3;
    *(uint4*)(&dst[r * LDS_STRIDE + seg * 8]) =
        *(const uint4*)(&src[(long)r * srcStride + seg * 8]);
  }
}

__device__ __forceinline__ void mfma_tile(const u16* As, const u16* Bs, int lane,
                                          int wm, int wn, f4v acc[4][4]) {
  const int rl = lane & 15;
  const int ks = (lane >> 4) * 8;
  s8v a[4], b[4];
#pragma unroll
  for (int m = 0; m < 4; ++m)
    a[m] = *(const s8v*)(&As[(wm * 64 + m * 16 + rl) * LDS_STRIDE + ks]);
#pragma unroll
  for (int n = 0; n < 4; ++n)
    b[n] = *(const s8v*)(&Bs[(wn * 64 + n * 16 + rl) * LDS_STRIDE + ks]);
#pragma unroll
  for (int m = 0; m < 4; ++m)
#pragma unroll
    for (int n = 0; n < 4; ++n)
      acc[m][n] = __builtin_amdgcn_mfma_f32_16x16x32_bf16(a[m], b[n], acc[m][n], 0, 0, 0);
}

__device__ __forceinline__ void zero_acc(f4v acc[4][4]) {
  f4v z = {0.f, 0.f, 0.f, 0.f};
#pragma unroll
  for (int m = 0; m < 4; ++m)
#pragma unroll
    for (int n = 0; n < 4; ++n) acc[m][n] = z;
}

// ---------------- converts ----------------

__global__ void convert_x_kernel(const float* __restrict__ in, u16* __restrict__ out) {
  int i = (blockIdx.x * 256 + threadIdx.x) * 4;
  float4 v = *(const float4*)(&in[i]);
  out[i + 0] = f2bf(v.x);
  out[i + 1] = f2bf(v.y);
  out[i + 2] = f2bf(v.z);
  out[i + 3] = f2bf(v.w);
}

__global__ void transpose_convert_kernel(const float* __restrict__ in, u16* __restrict__ out,
                                         int R, int C) {
  __shared__ float tile[32][33];
  int c0 = blockIdx.x * 32, r0 = blockIdx.y * 32;
  for (int rr = threadIdx.y; rr < 32; rr += 8)
    tile[rr][threadIdx.x] = in[(size_t)(r0 + rr) * C + (c0 + threadIdx.x)];
  __syncthreads();
  for (int cc = threadIdx.y; cc < 32; cc += 8)
    out[(size_t)(c0 + cc) * R + (r0 + threadIdx.x)] = f2bf(tile[threadIdx.x][cc]);
}

// ---------------- qkv projection with LDS-staged slab epilogue ----------------
// col tile (bn) spans exactly one s and two heads; rows span one b, 128 n.
// Per head the output slab [bh][nn0..nn0+127][0..63] is 16 KB contiguous.

__global__ __launch_bounds__(256) void gemm_qkv_kernel(
    const u16* __restrict__ xb, const u16* __restrict__ wqkvT,
    u16* __restrict__ quS, u16* __restrict__ ku, u16* __restrict__ vu,
    u16* __restrict__ qcS, u16* __restrict__ kc, u16* __restrict__ vcN) {
  __shared__ u16 sh[10240];  // As | Bs, reused as 8192-elem out-stage
  u16* As = sh;
  u16* Bs = sh + 5120;
  int bm = blockIdx.x, bn = blockIdx.y;
  int tid = threadIdx.x, lane = tid & 63, w = tid >> 6, wm = w >> 1, wn = w & 1;
  int g = lane >> 4, l15 = lane & 15;
  f4v acc[4][4];
  zero_acc(acc);
  for (int kk = 0; kk < 1024; kk += 32) {
    stage_tile(As, xb + (size_t)(bm * 128) * 1024 + kk, 128, 1024, tid, 256);
    stage_tile(Bs, wqkvT + (size_t)(bn * 128) * 1024 + kk, 128, 1024, tid, 256);
    __syncthreads();
    mfma_tile(As, Bs, lane, wm, wn, acc);
    __syncthreads();
  }
  int s = bn >> 3;             // qkv slot 0..5
  int b = bm >> 4;
  int nn0 = (bm & 15) * 128;
  int hh0 = (bn & 7) * 2;
  float scale = (s == 0 || s == 3) ? 0.125f : 1.f;
  u16* obase;
  switch (s) {
    case 0: obase = quS; break;
    case 1: obase = ku; break;
    case 2: obase = vu; break;
    case 3: obase = qcS; break;
    case 4: obase = kc; break;
    default: obase = vcN; break;
  }
#pragma unroll
  for (int pass = 0; pass < 2; ++pass) {
    __syncthreads();
    if (wn == pass) {
#pragma unroll
      for (int m = 0; m < 4; ++m)
#pragma unroll
        for (int n = 0; n < 4; ++n)
#pragma unroll
          for (int j = 0; j < 4; ++j) {
            int lrow = wm * 64 + m * 16 + g * 4 + j;
            int d = n * 16 + l15;
            sh[lrow * 64 + d] = f2bf(acc[m][n][j] * scale);
          }
    }
    __syncthreads();
    int bh = (b << 4) + hh0 + pass;
    u16* dst = obase + ((size_t)bh * 2048 + nn0) * 64;
    for (int it = 0; it < 4; ++it) {
      int e = (tid + it * 256) * 8;
      *(uint4*)(dst + e) = *(const uint4*)(&sh[e]);
    }
  }
}

// ------------- vcN [bh][n][d] -> vcT [bh][d][n] -------------

__global__ __launch_bounds__(256) void transpose_v_kernel(const u16* __restrict__ vcN,
                                                          u16* __restrict__ vcT) {
  __shared__ u16 t[64][72];
  int nt = blockIdx.x, bh = blockIdx.y;
  const u16* src = vcN + ((size_t)bh * 2048 + nt * 64) * 64;
  int tid = threadIdx.x;
  for (int i = tid; i < 512; i += 256) {
    int r = i >> 3, cseg = i & 7;
    *(uint4*)(&t[r][cseg * 8]) = *(const uint4*)(src + r * 64 + cseg * 8);
  }
  __syncthreads();
  u16* dst = vcT + (size_t)bh * 64 * 2048 + nt * 64;
  for (int i = tid; i < 512; i += 256) {
    int d = i >> 3, nseg = i & 7;
    u16 tmp[8];
#pragma unroll
    for (int e = 0; e < 8; ++e) tmp[e] = t[nseg * 8 + e][d];
    *(uint4*)(dst + (size_t)d * 2048 + nseg * 8) = *(uint4*)tmp;
  }
}

// ------------- term1 / lookahead -> packed swizzled tiles, coalesced writes -------------

__global__ __launch_bounds__(256) void tl_kernel(
    const u16* __restrict__ qcS, const u16* __restrict__ vu,
    const u16* __restrict__ quS, const u16* __restrict__ ku,
    u16* __restrict__ term1p, u16* __restrict__ lookp, int c0) {
  __shared__ u16 sh[10240];
  u16* As = sh;
  u16* Bs = sh + 5120;
  int t = blockIdx.x, lb = blockIdx.y, z = blockIdx.z;
  int bh = c0 + lb;
  int I = 0;
  while ((I + 1) * (I + 2) / 2 <= t) ++I;
  int K = t - I * (I + 1) / 2;
  int rt = z ? K : I;
  int ct = z ? I : K;
  const u16* A = (z ? quS : qcS) + ((size_t)bh * 2048 + rt * 128) * 64;
  const u16* B = (z ? ku : vu) + ((size_t)bh * 2048 + ct * 128) * 64;
  u16* o = (z ? lookp : term1p) + ((size_t)lb * 136 + t) * 16384;
  int tid = threadIdx.x, lane = tid & 63, w = tid >> 6, wm = w >> 1, wn = w & 1;
  int g = lane >> 4, l15 = lane & 15;
  f4v acc[4][4];
  zero_acc(acc);
  for (int kk = 0; kk < 64; kk += 32) {
    stage_tile(As, A + kk, 128, 64, tid, 256);
    stage_tile(Bs, B + kk, 128, 64, tid, 256);
    __syncthreads();
    mfma_tile(As, Bs, lane, wm, wn, acc);
    __syncthreads();
  }
  // two 64-row passes: scatter swizzled into LDS, copy linear (coalesced)
#pragma unroll
  for (int pass = 0; pass < 2; ++pass) {
    __syncthreads();
    if (wm == pass) {
#pragma unroll
      for (int m = 0; m < 4; ++m)
#pragma unroll
        for (int n = 0; n < 4; ++n)
#pragma unroll
          for (int j = 0; j < 4; ++j) {
            int lrl = m * 16 + g * 4 + j;          // 0..63 within pass
            int lc = wn * 64 + n * 16 + l15;
            int gr = rt * 128 + pass * 64 + lrl;
            int gc = ct * 128 + lc;
            float v = acc[m][n][j];
            if (z)
              v = (gc > gr) ? 1.f / (1.f + __expf(-v)) : 0.f;
            else
              v = (gc > gr) ? 0.f : v;
            sh[lrl * 128 + (lc ^ ((lrl & 7) << 3))] = f2bf(v);
          }
    }
    __syncthreads();
    for (int it = 0; it < 4; ++it) {
      int e = (tid + it * 256) * 8;
      *(uint4*)(o + pass * 8192 + e) = *(const uint4*)(&sh[e]);
    }
  }
}

// ------------- castle: per (I,K) tile, Su -> -silu -> +Sc -> mask -> softmax -> PV -------------

__global__ __launch_bounds__(256, 2) void castle_kernel(
    const u16* __restrict__ term1p, const u16* __restrict__ lookp,
    const u16* __restrict__ qcS, const u16* __restrict__ kc,
    const u16* __restrict__ vcT,
    u16* __restrict__ opart, float* __restrict__ ml, int c0) {
  __shared__ u16 sA[16384];  // term1 j-tile (swizzled) / P tile
  __shared__ u16 sB[16384];  // look j-tile / [Ks | Vs]
  int sid = blockIdx.x, lb = blockIdx.y, bh = c0 + lb;
  // decode: I descending (work-heaviest rows first), K ascending within row
  int I = 15, rem = sid;
  while (rem > I) { rem -= I + 1; --I; }
  int K = rem;
  int t = I * (I + 1) / 2 + K;

  int tid = threadIdx.x, lane = tid & 63, w = tid >> 6;
  int g = lane >> 4, l15 = lane & 15;

  const u16* t1b = term1p + (size_t)lb * 136 * 16384;
  const u16* lkb = lookp + (size_t)lb * 136 * 16384;

  // qc fragments in registers (reused for Sc)
  s8v qa[2][2];
#pragma unroll
  for (int mg = 0; mg < 2; ++mg)
#pragma unroll
    for (int kk = 0; kk < 2; ++kk)
      qa[mg][kk] = *(const s8v*)(&qcS[((size_t)bh * 2048 + I * 128 + w * 32 + mg * 16 + l15) * 64 +
                                      kk * 32 + g * 8]);

  f4v su[2][8];
  {
    f4v z = {0.f, 0.f, 0.f, 0.f};
#pragma unroll
    for (int mg = 0; mg < 2; ++mg)
#pragma unroll
      for (int n = 0; n < 8; ++n) su[mg][n] = z;
  }

  int bo = w * 1024 + (lane << 4);  // per-thread byte slot for staging

  // ---- Su over j in [K..I] ----
  for (int j = K; j <= I; ++j) {
    __syncthreads();
    const char* srcA = (const char*)(t1b + (size_t)(I * (I + 1) / 2 + j) * 16384);
    const char* srcB = (const char*)(lkb + (size_t)(j * (j + 1) / 2 + K) * 16384);
#pragma unroll
    for (int it = 0; it < 8; ++it) {
      gld16(srcA + bo + it * 4096, (char*)sA + bo + it * 4096);
      gld16(srcB + bo + it * 4096, (char*)sB + bo + it * 4096);
    }
    __syncthreads();
#pragma unroll
    for (int kk = 0; kk < 4; ++kk) {
      s8v a[2], b[8];
      int c = kk * 32 + g * 8;
#pragma unroll
      for (int mg = 0; mg < 2; ++mg)
        a[mg] = *(const s8v*)(&sA[swz128(w * 32 + mg * 16 + l15, c)]);
#pragma unroll
      for (int n = 0; n < 8; ++n)
        b[n] = *(const s8v*)(&sB[swz128(n * 16 + l15, c)]);
#pragma unroll
      for (int mg = 0; mg < 2; ++mg)
#pragma unroll
        for (int n = 0; n < 8; ++n)
          su[mg][n] = __builtin_amdgcn_mfma_f32_16x16x32_bf16(a[mg], b[n], su[mg][n], 0, 0, 0);
    }
  }

  // ---- stage Ks (kc tile) and Vs (vc slice) into sB, overlap with silu ----
  __syncthreads();
  {
#pragma unroll
    for (int it = 0; it < 4; ++it) {
      int o = bo + it * 4096;
      int row = o >> 7, lo = o & 127;
      const u16* src = kc + ((size_t)bh * 2048 + K * 128 + row) * 64 +
                       ((lo ^ ((row & 7) << 4)) >> 1);
      gld16(src, (char*)sB + o);
    }
#pragma unroll
    for (int it = 0; it < 4; ++it) {
      int o = bo + it * 4096;
      int rowd = o >> 8, lo = o & 255;
      const u16* src = vcT + ((size_t)bh * 64 + rowd) * 2048 + K * 128 +
                       ((lo ^ ((rowd & 7) << 4)) >> 1);
      gld16(src, (char*)sB + 16384 + o);
    }
  }
#pragma unroll
  for (int mg = 0; mg < 2; ++mg)
#pragma unroll
    for (int n = 0; n < 8; ++n)
#pragma unroll
      for (int j4 = 0; j4 < 4; ++j4) {
        float xv = su[mg][n][j4];
        su[mg][n][j4] = -(xv / (1.f + __expf(-xv)));
      }
  __syncthreads();

  // ---- Sc accumulate ----
#pragma unroll
  for (int kk = 0; kk < 2; ++kk) {
    s8v b[8];
    int c = kk * 32 + g * 8;
#pragma unroll
    for (int n = 0; n < 8; ++n)
      b[n] = *(const s8v*)(&sB[swz64v(n * 16 + l15, c)]);
#pragma unroll
    for (int mg = 0; mg < 2; ++mg)
#pragma unroll
      for (int n = 0; n < 8; ++n)
        su[mg][n] = __builtin_amdgcn_mfma_f32_16x16x32_bf16(qa[mg][kk], b[n], su[mg][n], 0, 0, 0);
  }

  // ---- causal mask (diagonal tile only) ----
  if (K == I) {
#pragma unroll
    for (int mg = 0; mg < 2; ++mg)
#pragma unroll
      for (int n = 0; n < 8; ++n)
#pragma unroll
        for (int j4 = 0; j4 < 4; ++j4) {
          int lr = w * 32 + mg * 16 + g * 4 + j4;
          int lc = n * 16 + l15;
          if (lc > lr) su[mg][n][j4] = -3.0e38f;
        }
  }

  // ---- local softmax ----
  float mrow[2][4], lrow[2][4];
#pragma unroll
  for (int mg = 0; mg < 2; ++mg)
#pragma unroll
    for (int j4 = 0; j4 < 4; ++j4) {
      float v = -3.0e38f;
#pragma unroll
      for (int n = 0; n < 8; ++n) v = fmaxf(v, su[mg][n][j4]);
      v = fmaxf(v, __shfl_xor(v, 1));
      v = fmaxf(v, __shfl_xor(v, 2));
      v = fmaxf(v, __shfl_xor(v, 4));
      v = fmaxf(v, __shfl_xor(v, 8));
      mrow[mg][j4] = v;
    }
  __syncthreads();
#pragma unroll
  for (int mg = 0; mg < 2; ++mg)
#pragma unroll
    for (int j4 = 0; j4 < 4; ++j4) {
      float sum = 0.f;
      int prow = w * 32 + mg * 16 + g * 4 + j4;
#pragma unroll
      for (int n = 0; n < 8; ++n) {
        float e = __expf(su[mg][n][j4] - mrow[mg][j4]);
        sum += e;
        sA[swz128(prow, n * 16 + l15)] = f2bf(e);
      }
      sum += __shfl_xor(sum, 1);
      sum += __shfl_xor(sum, 2);
      sum += __shfl_xor(sum, 4);
      sum += __shfl_xor(sum, 8);
      lrow[mg][j4] = sum;
    }
  __syncthreads();

  // ---- PV: O = P @ Vs ----
  f4v o[2][4];
  {
    f4v z = {0.f, 0.f, 0.f, 0.f};
#pragma unroll
    for (int mg = 0; mg < 2; ++mg)
#pragma unroll
      for (int nd = 0; nd < 4; ++nd) o[mg][nd] = z;
  }
#pragma unroll
  for (int kk = 0; kk < 4; ++kk) {
    s8v pa[2], vb[4];
    int c = kk * 32 + g * 8;
#pragma unroll
    for (int mg = 0; mg < 2; ++mg)
      pa[mg] = *(const s8v*)(&sA[swz128(w * 32 + mg * 16 + l15, c)]);
#pragma unroll
    for (int nd = 0; nd < 4; ++nd)
      vb[nd] = *(const s8v*)(&sB[8192 + swz128(nd * 16 + l15, c)]);
#pragma unroll
    for (int mg = 0; mg < 2; ++mg)
#pragma unroll
      for (int nd = 0; nd < 4; ++nd)
        o[mg][nd] = __builtin_amdgcn_mfma_f32_16x16x32_bf16(pa[mg], vb[nd], o[mg][nd], 0, 0, 0);
  }

  // ---- write partials ----
  size_t tb = (size_t)lb * 136 + t;
#pragma unroll
  for (int mg = 0; mg < 2; ++mg)
#pragma unroll
    for (int nd = 0; nd < 4; ++nd)
#pragma unroll
      for (int j4 = 0; j4 < 4; ++j4) {
        int prow = w * 32 + mg * 16 + g * 4 + j4;
        int dcol = nd * 16 + l15;
        opart[(tb * 128 + prow) * 64 + dcol] = f2bf(o[mg][nd][j4]);
      }
  if (l15 == 0) {
#pragma unroll
    for (int mg = 0; mg < 2; ++mg)
#pragma unroll
      for (int j4 = 0; j4 < 4; ++j4) {
        int prow = w * 32 + mg * 16 + g * 4 + j4;
        ml[tb * 256 + prow] = mrow[mg][j4];
        ml[tb * 256 + 128 + prow] = lrow[mg][j4];
      }
  }
}

// ------------- combine: flash-merge the <=16 partials per (I, head) -------------

__global__ __launch_bounds__(256) void combine_kernel(const u16* __restrict__ opart,
                                                      const float* __restrict__ ml,
                                                      u16* __restrict__ attn, int c0) {
  int lb = blockIdx.x, I = blockIdx.y, bh = c0 + lb;
  int tid = threadIdx.x;
  int row = tid >> 1, dh = (tid & 1) << 5;
  float M = -3.0e38f, L = 0.f;
  float O[32];
#pragma unroll
  for (int i = 0; i < 32; ++i) O[i] = 0.f;
  for (int K = 0; K <= I; ++K) {
    size_t tb = (size_t)lb * 136 + I * (I + 1) / 2 + K;
    float m = ml[tb * 256 + row];
    float l = ml[tb * 256 + 128 + row];
    float newM = fmaxf(M, m);
    float so = __expf(M - newM), sn = __expf(m - newM);
    L = L * so + l * sn;
    const u16* op = opart + (tb * 128 + row) * 64 + dh;
#pragma unroll
    for (int q = 0; q < 4; ++q) {
      s8v ov = *(const s8v*)(op + q * 8);
#pragma unroll
      for (int e = 0; e < 8; ++e)
        O[q * 8 + e] = O[q * 8 + e] * so + bf2f((u16)ov[e]) * sn;
    }
    M = newM;
  }
  float inv = 1.f / L;
  int b = bh >> 4, hh = bh & 15;
  u16* dst = attn + ((size_t)b * 2048 + I * 128 + row) * 1024 + hh * 64 + dh;
#pragma unroll
  for (int i = 0; i < 32; ++i) dst[i] = f2bf(O[i] * inv);
}

// ------------- final: out = attn_out @ W_out, f32 -------------

__global__ __launch_bounds__(256) void gemm_out_kernel(const u16* __restrict__ attn,
                                                       const u16* __restrict__ woutT,
                                                       float* __restrict__ out) {
  __shared__ u16 sh[10240];
  u16* As = sh;
  u16* Bs = sh + 5120;
  int bm = blockIdx.x, bn = blockIdx.y;
  int tid = threadIdx.x, lane = tid & 63, w = tid >> 6, wm = w >> 1, wn = w & 1;
  f4v acc[4][4];
  zero_acc(acc);
  for (int kk = 0; kk < 1024; kk += 32) {
    stage_tile(As, attn + (size_t)(bm * 128) * 1024 + kk, 128, 1024, tid, 256);
    stage_tile(Bs, woutT + (size_t)(bn * 128) * 1024 + kk, 128, 1024, tid, 256);
    __syncthreads();
    mfma_tile(As, Bs, lane, wm, wn, acc);
    __syncthreads();
  }
#pragma unroll
  for (int m = 0; m < 4; ++m)
#pragma unroll
    for (int n = 0; n < 4; ++n)
#pragma unroll
      for (int j = 0; j < 4; ++j) {
        int row = bm * 128 + wm * 64 + m * 16 + ((lane >> 4) * 4) + j;
        int col = bn * 128 + wn * 64 + n * 16 + (lane & 15);
        out[(size_t)row * 1024 + col] = acc[m][n][j];
      }
}

// ---------------- host ----------------

extern "C" void kernel_launch(void* const* d_in, const int* in_sizes, int n_in,
                              void* d_out, int out_size, void* d_ws, size_t ws_size,
                              hipStream_t stream) {
  const float* x = (const float*)d_in[0];
  const float* Wqkv = (const float*)d_in[1];
  const float* Wout = (const float*)d_in[2];
  float* out = (float*)d_out;

  char* base = (char*)d_ws;
  size_t off = 0;
  auto alloc = [&](size_t bytes) -> void* {
    void* p = base + off;
    off += (bytes + 255) & ~(size_t)255;
    return p;
  };

  // fixed-live buffers
  u16* woutT = (u16*)alloc(1024ull * 1024 * 2);
  u16* quS = (u16*)alloc(32ull * 2048 * 64 * 2);
  u16* ku = (u16*)alloc(32ull * 2048 * 64 * 2);
  u16* vu = (u16*)alloc(32ull * 2048 * 64 * 2);
  u16* qcS = (u16*)alloc(32ull * 2048 * 64 * 2);
  u16* kc = (u16*)alloc(32ull * 2048 * 64 * 2);
  u16* vcN = (u16*)alloc(32ull * 2048 * 64 * 2);
  u16* vcT = (u16*)alloc(32ull * 2048 * 64 * 2);
  u16* attn = (u16*)alloc(4096ull * 1024 * 2);

  // per-head chunk scratch: packed term1 + packed look + opart(bf16) + ml(f32)
  size_t perBH = 136ull * 16384 * 2 * 2 + 136ull * 128 * 64 * 2 + 136ull * 256 * 4;
  size_t remain = (ws_size > off) ? (ws_size - off) : 0;
  int chunk = (int)(remain / perBH);
  if (chunk < 1) chunk = 1;
  if (chunk > 16) chunk = 16;  // keep per-launch working set L3-resident
  u16* term1p = (u16*)alloc((size_t)chunk * 136 * 16384 * 2);
  u16* lookp = (u16*)alloc((size_t)chunk * 136 * 16384 * 2);
  u16* opart = (u16*)alloc((size_t)chunk * 136 * 8192 * 2);
  float* mlb = (float*)alloc((size_t)chunk * 136 * 256 * 4);

  // xb / wqkvT are dead after gemm_qkv -> overlay on chunk region if it fits
  u16* xb;
  u16* wqkvT;
  if ((size_t)chunk * 136 * 16384 * 2 >= (4096ull + 6144ull) * 1024 * 2) {
    xb = term1p;
    wqkvT = term1p + 4096ull * 1024;
  } else {
    xb = (u16*)alloc(4096ull * 1024 * 2);
    wqkvT = (u16*)alloc(6144ull * 1024 * 2);
  }

  convert_x_kernel<<<4096, 256, 0, stream>>>(x, xb);
  transpose_convert_kernel<<<dim3(192, 32), dim3(32, 8), 0, stream>>>(Wqkv, wqkvT, 1024, 6144);
  transpose_convert_kernel<<<dim3(32, 32), dim3(32, 8), 0, stream>>>(Wout, woutT, 1024, 1024);
  gemm_qkv_kernel<<<dim3(32, 48), 256, 0, stream>>>(xb, wqkvT, quS, ku, vu, qcS, kc, vcN);
  transpose_v_kernel<<<dim3(32, 32), 256, 0, stream>>>(vcN, vcT);

  for (int c0 = 0; c0 < 32; c0 += chunk) {
    int nb = (32 - c0 < chunk) ? (32 - c0) : chunk;
    tl_kernel<<<dim3(136, nb, 2), 256, 0, stream>>>(qcS, vu, quS, ku, term1p, lookp, c0);
    castle_kernel<<<dim3(136, nb), 256, 0, stream>>>(term1p, lookp, qcS, kc, vcT, opart, mlb, c0);
    combine_kernel<<<dim3(nb, 16), 256, 0, stream>>>(opart, mlb, attn, c0);
  }
  gemm_out_kernel<<<dim3(32, 8), 256, 0, stream>>>(attn, woutT, out);
}